// Round 1
// baseline (155.755 us; speedup 1.0000x reference)
//
#include <hip/hip_runtime.h>
#include <hip/hip_bf16.h>

// ContrastiveLoss fused kernel for MI355X (gfx950).
//
// Math reduction (T=0.5):
//   f = x / max(||x||, 1e-8)   (rows)
//   s_ij = f_i . f_j
//   den_i = sum_{j: label_j != label_i} exp(2 s_ij)
//   loss  = sum_i [ c_i * log(den_i) - sum_{j same label, j != i} 2 s_ij ]
//           / (sum_i c_i + 1e-5),   c_i = count(label_i) - 1
// (different-label & diagonal entries of loss_mat are exactly 1 -> -log = 0,
//  so they contribute neither to the sum nor to count_nonzero.)
//
// Problem is fixed-shape: N=4096, D=512, labels in [0,100).

typedef short short8 __attribute__((ext_vector_type(8)));
typedef float floatx4 __attribute__((ext_vector_type(4)));
typedef unsigned short u16;
typedef unsigned int u32;

#define N_ROWS 4096
#define DIM 512
#define EPS_NORM 1e-8f
#define EPS_DEN 1e-5f
#define BI 64               // rows per block (4 waves x 16)
#define JCH 8               // j-range split
#define NBLK_I (N_ROWS / BI)

static __device__ inline u16 f32_to_bf16(float f) {
  u32 u = __float_as_uint(f);
  u32 r = (u + 0x7FFFu + ((u >> 16) & 1u)) >> 16;   // round-to-nearest-even
  return (u16)r;
}

__global__ void k0_init(float* __restrict__ den, float* __restrict__ pos,
                        int* __restrict__ hist) {
  int t = blockIdx.x * blockDim.x + threadIdx.x;
  if (t < N_ROWS) { den[t] = 0.f; pos[t] = 0.f; }
  if (t < 128) hist[t] = 0;
}

// one block per row, 128 threads, float4 per thread
__global__ void k1_normalize(const float* __restrict__ x,
                             const int* __restrict__ labels,
                             u16* __restrict__ fb, int* __restrict__ hist) {
  const int row = blockIdx.x;
  const int tid = threadIdx.x;
  float4 v = reinterpret_cast<const float4*>(x + (size_t)row * DIM)[tid];
  float ss = v.x * v.x + v.y * v.y + v.z * v.z + v.w * v.w;
#pragma unroll
  for (int m = 1; m < 64; m <<= 1) ss += __shfl_xor(ss, m, 64);
  __shared__ float sred[2];
  if ((tid & 63) == 0) sred[tid >> 6] = ss;
  __syncthreads();
  float total = sred[0] + sred[1];
  float scale = 1.f / fmaxf(sqrtf(total), EPS_NORM);
  u32 w0 = ((u32)f32_to_bf16(v.y * scale) << 16) | (u32)f32_to_bf16(v.x * scale);
  u32 w1 = ((u32)f32_to_bf16(v.w * scale) << 16) | (u32)f32_to_bf16(v.z * scale);
  uint2 o; o.x = w0; o.y = w1;
  reinterpret_cast<uint2*>(fb + (size_t)row * DIM)[tid] = o;
  if (tid == 0) atomicAdd(&hist[labels[row]], 1);
}

// fused sim-GEMM + per-row reduction.
// grid = NBLK_I * JCH blocks, 256 threads (4 waves), wave w owns 16 rows.
__global__ __launch_bounds__(256, 2) void k2_fused(
    const u16* __restrict__ fb, const int* __restrict__ labels,
    float* __restrict__ den, float* __restrict__ pos) {
  const int bid = blockIdx.x;
  const int itile = bid % NBLK_I;
  const int jch = bid / NBLK_I;
  const int tid = threadIdx.x;
  const int wv = tid >> 6;
  const int lane = tid & 63;
  const int l15 = lane & 15;
  const int kg = lane >> 4;          // 0..3 (k-group)

  // A fragments: 16 rows x 512 k, register-resident for the whole j loop.
  // layout: lane holds A[row = lane&15][k = kt*32 + kg*8 + e], e=0..7 contiguous
  const int arow = itile * BI + wv * 16 + l15;
  short8 a[16];
#pragma unroll
  for (int kt = 0; kt < 16; ++kt)
    a[kt] = *reinterpret_cast<const short8*>(fb + (size_t)arow * DIM + kt * 32 + kg * 8);

  // C/D layout (verified gfx950): col = lane&15, row = (lane>>4)*4 + r
  int i_idx[4]; int labi[4];
#pragma unroll
  for (int r = 0; r < 4; ++r) {
    i_idx[r] = itile * BI + wv * 16 + kg * 4 + r;
    labi[r] = labels[i_idx[r]];
  }

  float den_acc[4] = {0.f, 0.f, 0.f, 0.f};
  float pos_acc[4] = {0.f, 0.f, 0.f, 0.f};

  const int jspan = N_ROWS / JCH;
  const int jbase0 = jch * jspan;
  for (int jt = 0; jt < jspan / 16; ++jt) {
    const int jrow = jbase0 + jt * 16 + l15;   // B col for this lane (== C col)
    const int labj = labels[jrow];
    floatx4 acc = {0.f, 0.f, 0.f, 0.f};
#pragma unroll
    for (int kt = 0; kt < 16; ++kt) {
      short8 b = *reinterpret_cast<const short8*>(fb + (size_t)jrow * DIM + kt * 32 + kg * 8);
      acc = __builtin_amdgcn_mfma_f32_16x16x32_bf16(a[kt], b, acc, 0, 0, 0);
    }
#pragma unroll
    for (int r = 0; r < 4; ++r) {
      float s2 = 2.f * acc[r];                 // sim / T
      float e = __expf(s2);
      bool same = (labj == labi[r]);
      den_acc[r] += same ? 0.f : e;
      pos_acc[r] += (same && (jrow != i_idx[r])) ? s2 : 0.f;
    }
  }

  // reduce across the 16 cols (lanes sharing lane>>4), then one atomic per row
#pragma unroll
  for (int r = 0; r < 4; ++r) {
    float d = den_acc[r], p = pos_acc[r];
#pragma unroll
    for (int m = 1; m < 16; m <<= 1) {
      d += __shfl_xor(d, m, 64);
      p += __shfl_xor(p, m, 64);
    }
    if (l15 == 0) {
      atomicAdd(&den[i_idx[r]], d);
      atomicAdd(&pos[i_idx[r]], p);
    }
  }
}

__global__ void k3_final(const float* __restrict__ den, const float* __restrict__ pos,
                         const int* __restrict__ labels, const int* __restrict__ hist,
                         float* __restrict__ out) {
  const int tid = threadIdx.x;   // 256 threads, 1 block
  float num = 0.f, nnz = 0.f;
  for (int i = tid; i < N_ROWS; i += 256) {
    int c = hist[labels[i]] - 1;
    num += (float)c * logf(den[i]) - pos[i];
    nnz += (float)c;
  }
#pragma unroll
  for (int m = 1; m < 64; m <<= 1) {
    num += __shfl_xor(num, m, 64);
    nnz += __shfl_xor(nnz, m, 64);
  }
  __shared__ float sn[4], sz[4];
  if ((tid & 63) == 0) { sn[tid >> 6] = num; sz[tid >> 6] = nnz; }
  __syncthreads();
  if (tid == 0) {
    float tn = sn[0] + sn[1] + sn[2] + sn[3];
    float tz = sz[0] + sz[1] + sz[2] + sz[3];
    out[0] = tn / (tz + EPS_DEN);
  }
}

extern "C" void kernel_launch(void* const* d_in, const int* in_sizes, int n_in,
                              void* d_out, int out_size, void* d_ws, size_t ws_size,
                              hipStream_t stream) {
  const float* x = (const float*)d_in[0];
  const int* labels = (const int*)d_in[1];

  // ws layout: fb (bf16 4096x512 = 4MB) | den f32[4096] | pos f32[4096] | hist i32[128]
  u16* fb = (u16*)d_ws;
  float* den = (float*)((char*)d_ws + (size_t)N_ROWS * DIM * 2);
  float* pos = den + N_ROWS;
  int* hist = (int*)(pos + N_ROWS);
  float* out = (float*)d_out;

  hipLaunchKernelGGL(k0_init, dim3((N_ROWS + 255) / 256), dim3(256), 0, stream,
                     den, pos, hist);
  hipLaunchKernelGGL(k1_normalize, dim3(N_ROWS), dim3(128), 0, stream,
                     x, labels, fb, hist);
  hipLaunchKernelGGL(k2_fused, dim3(NBLK_I * JCH), dim3(256), 0, stream,
                     fb, labels, den, pos);
  hipLaunchKernelGGL(k3_final, dim3(1), dim3(256), 0, stream,
                     den, pos, labels, hist, out);
}

// Round 2
// 63.029 us; speedup vs baseline: 2.4712x; 2.4712x over previous
//
#include <hip/hip_runtime.h>
#include <hip/hip_bf16.h>

// ContrastiveLoss fused kernel for MI355X (gfx950).
//
// Math reduction (T=0.5):
//   f = x / max(||x||, 1e-8)   (rows)
//   s_ij = f_i . f_j
//   den_i = sum_{j: label_j != label_i} exp(2 s_ij)
//   loss  = sum_i [ c_i * log(den_i) - sum_{j same label, j != i} 2 s_ij ]
//           / (sum_i c_i + 1e-5),   c_i = count(label_i) - 1
//
// N=4096, D=512, labels in [0,100).
//
// k2 design (round 2): block = 256 thr (4 waves), i-tile 128 rows
// (32/wave via 2 A-sets pinned in 128 VGPRs), j-chunk 256 cols.
// B tiles (16 rows x 512 = 16 KB) staged global->LDS (width 16),
// double-buffered, XOR-swizzled ((row&15)<<4) via pre-swizzled source.

typedef short short8 __attribute__((ext_vector_type(8)));
typedef float floatx4 __attribute__((ext_vector_type(4)));
typedef unsigned short u16;
typedef unsigned int u32;

#define N_ROWS 4096
#define DIM 512
#define ROWB 1024           // bytes per row
#define EPS_NORM 1e-8f
#define EPS_DEN 1e-5f
#define BI 128              // i-rows per block (4 waves x 32)
#define NBLK_I (N_ROWS / BI)   // 32
#define JCH 16
#define JSPAN (N_ROWS / JCH)   // 256
#define NJT (JSPAN / 16)       // 16

static __device__ inline u16 f32_to_bf16(float f) {
  u32 u = __float_as_uint(f);
  u32 r = (u + 0x7FFFu + ((u >> 16) & 1u)) >> 16;   // RNE
  return (u16)r;
}

static __device__ inline void load_lds16(const char* g, char* l) {
  __builtin_amdgcn_global_load_lds(
      (const __attribute__((address_space(1))) void*)g,
      (__attribute__((address_space(3))) void*)l, 16, 0, 0);
}

__global__ void k0_init(int* __restrict__ hist) {
  if (threadIdx.x < 128) hist[threadIdx.x] = 0;
}

// one block per row, 128 threads; also zeroes den/pos for that row
__global__ void k1_normalize(const float* __restrict__ x,
                             const int* __restrict__ labels,
                             u16* __restrict__ fb, int* __restrict__ hist,
                             float* __restrict__ den, float* __restrict__ pos) {
  const int row = blockIdx.x;
  const int tid = threadIdx.x;
  float4 v = reinterpret_cast<const float4*>(x + (size_t)row * DIM)[tid];
  float ss = v.x * v.x + v.y * v.y + v.z * v.z + v.w * v.w;
#pragma unroll
  for (int m = 1; m < 64; m <<= 1) ss += __shfl_xor(ss, m, 64);
  __shared__ float sred[2];
  if ((tid & 63) == 0) sred[tid >> 6] = ss;
  __syncthreads();
  float total = sred[0] + sred[1];
  float scale = 1.f / fmaxf(sqrtf(total), EPS_NORM);
  u32 w0 = ((u32)f32_to_bf16(v.y * scale) << 16) | (u32)f32_to_bf16(v.x * scale);
  u32 w1 = ((u32)f32_to_bf16(v.w * scale) << 16) | (u32)f32_to_bf16(v.z * scale);
  uint2 o; o.x = w0; o.y = w1;
  reinterpret_cast<uint2*>(fb + (size_t)row * DIM)[tid] = o;
  if (tid == 0) {
    atomicAdd(&hist[labels[row]], 1);
    den[row] = 0.f;
    pos[row] = 0.f;
  }
}

// fused sim-GEMM + per-row reduction.
__global__ __launch_bounds__(256, 2) void k2_fused(
    const u16* __restrict__ fb, const int* __restrict__ labels,
    float* __restrict__ den, float* __restrict__ pos) {
  __shared__ u16 Bsh[2 * 16 * DIM];       // 2 x 16 KB, swizzled
  __shared__ int labj_sh[JSPAN];

  const char* fbb = (const char*)fb;
  char* bshb = (char*)Bsh;

  const int bid = blockIdx.x;
  const int itile = bid & (NBLK_I - 1);
  const int jch = bid >> 5;               // NBLK_I == 32
  const int tid = threadIdx.x;
  const int wv = tid >> 6;
  const int lane = tid & 63;
  const int l15 = lane & 15;
  const int kg = lane >> 4;               // 0..3

  const int ib = itile * BI;
  const int jbase = jch * JSPAN;

  // stage 16 B-rows starting at global row (grow) into LDS half (bufsel).
  // LDS layout: row r (0..15), byte col cs, stored at r*1024 + (cs ^ (r<<4)).
  // global_load_lds writes linearly -> pre-swizzle the SOURCE (rule #21).
#define STAGE(bufsel, grow) do {                                          \
    _Pragma("unroll")                                                     \
    for (int c_ = 0; c_ < 4; ++c_) {                                      \
      const int r_ = c_ * 4 + wv;                                         \
      const int cs_ = lane * 16;                                          \
      load_lds16(fbb + (size_t)((grow) + r_) * ROWB + (cs_ ^ (r_ << 4)),  \
                 bshb + (bufsel) * 16384 + r_ * ROWB + cs_);              \
    }                                                                     \
  } while (0)

  // prologue: stage jt=0 into buf 0, labels into LDS
  STAGE(0, jbase);
  labj_sh[tid] = labels[jbase + tid];

  // A fragments: 32 rows/wave (2 sets of 16), K=512, register-resident.
  // lane (kg,l15) holds A[row=set_base+l15][k = kt*32 + kg*8 + e]
  short8 a[2][16];
#pragma unroll
  for (int s = 0; s < 2; ++s) {
    const char* arow = fbb + (size_t)(ib + wv * 32 + s * 16 + l15) * ROWB + kg * 16;
#pragma unroll
    for (int kt = 0; kt < 16; ++kt)
      a[s][kt] = *reinterpret_cast<const short8*>(arow + kt * 64);
  }
  // pin A in VGPRs: forbid the compiler from sinking/rematerializing the
  // loads into the j-loop (round-1 pathology: VGPR_Count=56 proved sinking)
#pragma unroll
  for (int s = 0; s < 2; ++s)
#pragma unroll
    for (int kt = 0; kt < 16; ++kt)
      asm volatile("" : "+v"(a[s][kt]));

  // C/D layout (verified gfx950): col = lane&15 (j), row = kg*4 + r (i)
  int i_idx[2][4]; int labi[2][4];
#pragma unroll
  for (int s = 0; s < 2; ++s)
#pragma unroll
    for (int r = 0; r < 4; ++r) {
      i_idx[s][r] = ib + wv * 32 + s * 16 + kg * 4 + r;
      labi[s][r] = labels[i_idx[s][r]];
    }

  float den_acc[2][4] = {{0.f,0.f,0.f,0.f},{0.f,0.f,0.f,0.f}};
  float pos_acc[2][4] = {{0.f,0.f,0.f,0.f},{0.f,0.f,0.f,0.f}};

  __syncthreads();   // buf0 staged, labels ready

  for (int jt = 0; jt < NJT; ++jt) {
    const int cur = jt & 1;
    if (jt + 1 < NJT) STAGE(cur ^ 1, jbase + (jt + 1) * 16);

    const int j0 = jt * 16;
    const int jrow = jbase + j0 + l15;
    const int labj = labj_sh[j0 + l15];

    floatx4 acc0 = {0.f, 0.f, 0.f, 0.f};
    floatx4 acc1 = {0.f, 0.f, 0.f, 0.f};
    const char* bbase = bshb + cur * 16384 + l15 * ROWB;
    const int sw = l15 << 4;
#pragma unroll
    for (int kt = 0; kt < 16; ++kt) {
      short8 b = *reinterpret_cast<const short8*>(bbase + ((kt * 64 + kg * 16) ^ sw));
      acc0 = __builtin_amdgcn_mfma_f32_16x16x32_bf16(a[0][kt], b, acc0, 0, 0, 0);
      acc1 = __builtin_amdgcn_mfma_f32_16x16x32_bf16(a[1][kt], b, acc1, 0, 0, 0);
    }

#pragma unroll
    for (int s = 0; s < 2; ++s) {
#pragma unroll
      for (int r = 0; r < 4; ++r) {
        float sv = s ? acc1[r] : acc0[r];
        float s2 = 2.f * sv;                 // sim / T
        float e = __expf(s2);
        bool same = (labj == labi[s][r]);
        den_acc[s][r] += same ? 0.f : e;
        pos_acc[s][r] += (same && (jrow != i_idx[s][r])) ? s2 : 0.f;
      }
    }
    __syncthreads();   // staging for jt+1 done; safe to flip buffers
  }

  // reduce across the 16 cols (lanes with same kg), one atomic per row
#pragma unroll
  for (int s = 0; s < 2; ++s)
#pragma unroll
    for (int r = 0; r < 4; ++r) {
      float d = den_acc[s][r], p = pos_acc[s][r];
#pragma unroll
      for (int m = 1; m < 16; m <<= 1) {
        d += __shfl_xor(d, m, 64);
        p += __shfl_xor(p, m, 64);
      }
      if (l15 == 0) {
        atomicAdd(&den[i_idx[s][r]], d);
        atomicAdd(&pos[i_idx[s][r]], p);
      }
    }
#undef STAGE
}

__global__ void k3_final(const float* __restrict__ den, const float* __restrict__ pos,
                         const int* __restrict__ labels, const int* __restrict__ hist,
                         float* __restrict__ out) {
  const int tid = threadIdx.x;   // 256 threads, 1 block
  float num = 0.f, nnz = 0.f;
  for (int i = tid; i < N_ROWS; i += 256) {
    int c = hist[labels[i]] - 1;
    num += (float)c * logf(den[i]) - pos[i];
    nnz += (float)c;
  }
#pragma unroll
  for (int m = 1; m < 64; m <<= 1) {
    num += __shfl_xor(num, m, 64);
    nnz += __shfl_xor(nnz, m, 64);
  }
  __shared__ float sn[4], sz[4];
  if ((tid & 63) == 0) { sn[tid >> 6] = num; sz[tid >> 6] = nnz; }
  __syncthreads();
  if (tid == 0) {
    float tn = sn[0] + sn[1] + sn[2] + sn[3];
    float tz = sz[0] + sz[1] + sz[2] + sz[3];
    out[0] = tn / (tz + EPS_DEN);
  }
}

extern "C" void kernel_launch(void* const* d_in, const int* in_sizes, int n_in,
                              void* d_out, int out_size, void* d_ws, size_t ws_size,
                              hipStream_t stream) {
  const float* x = (const float*)d_in[0];
  const int* labels = (const int*)d_in[1];

  // ws layout: fb (bf16 4096x512 = 4MB) | den f32[4096] | pos f32[4096] | hist i32[128]
  u16* fb = (u16*)d_ws;
  float* den = (float*)((char*)d_ws + (size_t)N_ROWS * DIM * 2);
  float* pos = den + N_ROWS;
  int* hist = (int*)(pos + N_ROWS);
  float* out = (float*)d_out;

  hipLaunchKernelGGL(k0_init, dim3(1), dim3(128), 0, stream, hist);
  hipLaunchKernelGGL(k1_normalize, dim3(N_ROWS), dim3(128), 0, stream,
                     x, labels, fb, hist, den, pos);
  hipLaunchKernelGGL(k2_fused, dim3(NBLK_I * JCH), dim3(256), 0, stream,
                     fb, labels, den, pos);
  hipLaunchKernelGGL(k3_final, dim3(1), dim3(256), 0, stream,
                     den, pos, labels, hist, out);
}

// Round 3
// 52.066 us; speedup vs baseline: 2.9915x; 1.2106x over previous
//
#include <hip/hip_runtime.h>
#include <hip/hip_bf16.h>

// ContrastiveLoss fused kernel for MI355X (gfx950).
//
// Math reduction (T=0.5):
//   f = x / max(||x||, 1e-8)   (rows)
//   s_ij = f_i . f_j
//   den_i = sum_{j: label_j != label_i} exp(2 s_ij)
//   loss  = sum_i [ c_i * log(den_i) - sum_{j same label, j != i} 2 s_ij ]
//           / (sum_i c_i + 1e-5),   c_i = count(label_i) - 1
//
// N=4096, D=512, labels in [0,100).
//
// Round 3: k2 = 1024 blocks, 128i x 128j tile, 4 waves (32 i-rows/wave,
// A pinned in 128 VGPRs), j processed in 32-col slabs (4 per block),
// B staged global->LDS width-16, double-buffered, XOR-swizzled source.
// 4 independent MFMA chains per wave. k0 removed (hist in k3). k1 is
// wave-per-row.

typedef short short8 __attribute__((ext_vector_type(8)));
typedef float floatx4 __attribute__((ext_vector_type(4)));
typedef unsigned short u16;
typedef unsigned int u32;

#define N_ROWS 4096
#define DIM 512
#define ROWB 1024              // bytes per row
#define EPS_NORM 1e-8f
#define EPS_DEN 1e-5f
#define BI 128                 // i-rows per block (4 waves x 32)
#define NBLK_I (N_ROWS / BI)   // 32
#define JSPAN 128              // j-cols per block
#define NJT (JSPAN / 32)       // 4 slabs of 32

static __device__ inline u16 f32_to_bf16(float f) {
  u32 u = __float_as_uint(f);
  u32 r = (u + 0x7FFFu + ((u >> 16) & 1u)) >> 16;   // RNE
  return (u16)r;
}

static __device__ inline void load_lds16(const char* g, char* l) {
  __builtin_amdgcn_global_load_lds(
      (const __attribute__((address_space(1))) void*)g,
      (__attribute__((address_space(3))) void*)l, 16, 0, 0);
}

// wave-per-row normalize + bf16 pack; grid 1024 x 256
__global__ void k1_normalize(const float* __restrict__ x,
                             u16* __restrict__ fb,
                             float* __restrict__ den, float* __restrict__ pos) {
  const int row = blockIdx.x * 4 + (threadIdx.x >> 6);
  const int lane = threadIdx.x & 63;
  const float4* src = reinterpret_cast<const float4*>(x + (size_t)row * DIM);
  float4 v0 = src[lane * 2];
  float4 v1 = src[lane * 2 + 1];
  float ss = v0.x*v0.x + v0.y*v0.y + v0.z*v0.z + v0.w*v0.w
           + v1.x*v1.x + v1.y*v1.y + v1.z*v1.z + v1.w*v1.w;
#pragma unroll
  for (int m = 1; m < 64; m <<= 1) ss += __shfl_xor(ss, m, 64);
  float scale = 1.f / fmaxf(sqrtf(ss), EPS_NORM);
  uint4 o;
  o.x = ((u32)f32_to_bf16(v0.y * scale) << 16) | (u32)f32_to_bf16(v0.x * scale);
  o.y = ((u32)f32_to_bf16(v0.w * scale) << 16) | (u32)f32_to_bf16(v0.z * scale);
  o.z = ((u32)f32_to_bf16(v1.y * scale) << 16) | (u32)f32_to_bf16(v1.x * scale);
  o.w = ((u32)f32_to_bf16(v1.w * scale) << 16) | (u32)f32_to_bf16(v1.z * scale);
  reinterpret_cast<uint4*>(fb + (size_t)row * DIM)[lane] = o;
  if (lane == 0) { den[row] = 0.f; pos[row] = 0.f; }
}

// fused sim-GEMM + per-row reduction.
__global__ __launch_bounds__(256, 2) void k2_fused(
    const u16* __restrict__ fb, const int* __restrict__ labels,
    float* __restrict__ den, float* __restrict__ pos) {
  __shared__ u16 Bsh[2 * 32 * DIM];       // 2 x 32 KB, swizzled
  __shared__ int labj_sh[JSPAN];

  const char* fbb = (const char*)fb;
  char* bshb = (char*)Bsh;

  const int bid = blockIdx.x;
  const int itile = bid & (NBLK_I - 1);
  const int jch = bid >> 5;               // 32 j-chunks
  const int tid = threadIdx.x;
  const int wv = tid >> 6;
  const int lane = tid & 63;
  const int l15 = lane & 15;
  const int kg = lane >> 4;               // 0..3

  const int ib = itile * BI;
  const int jbase = jch * JSPAN;

  // stage 32 B-rows (32 KB) starting at global row (grow) into LDS half.
  // LDS layout: row r (0..31), byte col cs at r*1024 + cs, with the SOURCE
  // pre-swizzled by ((r&15)<<4) so a swizzled read is correct (rule #21).
#define STAGE(bufsel, grow) do {                                               \
    _Pragma("unroll")                                                          \
    for (int i_ = 0; i_ < 8; ++i_) {                                           \
      const int r_ = i_ * 4 + wv;                                              \
      const int cs_ = lane * 16;                                               \
      load_lds16(fbb + (size_t)((grow) + r_) * ROWB + (cs_ ^ ((r_ & 15) << 4)),\
                 bshb + (bufsel) * 32768 + r_ * ROWB + cs_);                   \
    }                                                                          \
  } while (0)

  // prologue: stage slab 0 into buf 0, labels into LDS
  STAGE(0, jbase);
  if (tid < JSPAN) labj_sh[tid] = labels[jbase + tid];

  // A fragments: 32 rows/wave (2 sets of 16), K=512, register-resident.
  // lane (kg,l15) holds A[row = set_base + l15][k = kt*32 + kg*8 + e]
  short8 a[2][16];
#pragma unroll
  for (int s = 0; s < 2; ++s) {
    const char* arow = fbb + (size_t)(ib + wv * 32 + s * 16 + l15) * ROWB + kg * 16;
#pragma unroll
    for (int kt = 0; kt < 16; ++kt)
      a[s][kt] = *reinterpret_cast<const short8*>(arow + kt * 64);
  }
  // pin A in VGPRs (round-1 pathology: compiler sank loads into the loop)
#pragma unroll
  for (int s = 0; s < 2; ++s)
#pragma unroll
    for (int kt = 0; kt < 16; ++kt)
      asm volatile("" : "+v"(a[s][kt]));

  // C/D layout (verified gfx950): col = lane&15 (j), row = kg*4 + r (i)
  int i_idx[2][4]; int labi[2][4];
#pragma unroll
  for (int s = 0; s < 2; ++s)
#pragma unroll
    for (int r = 0; r < 4; ++r) {
      i_idx[s][r] = ib + wv * 32 + s * 16 + kg * 4 + r;
      labi[s][r] = labels[i_idx[s][r]];
    }

  float den_acc[2][4] = {{0.f,0.f,0.f,0.f},{0.f,0.f,0.f,0.f}};
  float pos_acc[2][4] = {{0.f,0.f,0.f,0.f},{0.f,0.f,0.f,0.f}};

  __syncthreads();   // buf0 staged, labels ready

  for (int jt = 0; jt < NJT; ++jt) {
    const int cur = jt & 1;
    if (jt + 1 < NJT) STAGE(cur ^ 1, jbase + (jt + 1) * 32);

    const int j0 = jt * 32;
    const int jrow0 = jbase + j0 + l15;        // js = 0
    const int jrow1 = jrow0 + 16;              // js = 1
    const int labj0 = labj_sh[j0 + l15];
    const int labj1 = labj_sh[j0 + 16 + l15];

    // 4 independent MFMA chains: (i-set 0/1) x (j-subtile 0/1)
    floatx4 acc00 = {0.f,0.f,0.f,0.f}, acc01 = {0.f,0.f,0.f,0.f};
    floatx4 acc10 = {0.f,0.f,0.f,0.f}, acc11 = {0.f,0.f,0.f,0.f};
    const char* b0base = bshb + cur * 32768 + l15 * ROWB;
    const char* b1base = b0base + 16 * ROWB;
    const int sw = l15 << 4;
#pragma unroll
    for (int kt = 0; kt < 16; ++kt) {
      const int off = (kt * 64 + kg * 16) ^ sw;
      short8 b0 = *reinterpret_cast<const short8*>(b0base + off);
      short8 b1 = *reinterpret_cast<const short8*>(b1base + off);
      acc00 = __builtin_amdgcn_mfma_f32_16x16x32_bf16(a[0][kt], b0, acc00, 0, 0, 0);
      acc10 = __builtin_amdgcn_mfma_f32_16x16x32_bf16(a[1][kt], b0, acc10, 0, 0, 0);
      acc01 = __builtin_amdgcn_mfma_f32_16x16x32_bf16(a[0][kt], b1, acc01, 0, 0, 0);
      acc11 = __builtin_amdgcn_mfma_f32_16x16x32_bf16(a[1][kt], b1, acc11, 0, 0, 0);
    }

#pragma unroll
    for (int s = 0; s < 2; ++s) {
      floatx4 aj0 = s ? acc10 : acc00;
      floatx4 aj1 = s ? acc11 : acc01;
#pragma unroll
      for (int r = 0; r < 4; ++r) {
        float s20 = 2.f * aj0[r];
        float s21 = 2.f * aj1[r];
        float e0 = __expf(s20);
        float e1 = __expf(s21);
        bool sm0 = (labj0 == labi[s][r]);
        bool sm1 = (labj1 == labi[s][r]);
        den_acc[s][r] += (sm0 ? 0.f : e0) + (sm1 ? 0.f : e1);
        float p = 0.f;
        if (sm0 && (jrow0 != i_idx[s][r])) p += s20;
        if (sm1 && (jrow1 != i_idx[s][r])) p += s21;
        pos_acc[s][r] += p;
      }
    }
    __syncthreads();   // staging for jt+1 done; safe to flip buffers
  }

  // reduce across the 16 cols (lanes with same kg), one atomic per row
#pragma unroll
  for (int s = 0; s < 2; ++s)
#pragma unroll
    for (int r = 0; r < 4; ++r) {
      float d = den_acc[s][r], p = pos_acc[s][r];
#pragma unroll
      for (int m = 1; m < 16; m <<= 1) {
        d += __shfl_xor(d, m, 64);
        p += __shfl_xor(p, m, 64);
      }
      if (l15 == 0) {
        atomicAdd(&den[i_idx[s][r]], d);
        atomicAdd(&pos[i_idx[s][r]], p);
      }
    }
#undef STAGE
}

__global__ void k3_final(const float* __restrict__ den, const float* __restrict__ pos,
                         const int* __restrict__ labels, float* __restrict__ out) {
  const int tid = threadIdx.x;   // 256 threads, 1 block
  __shared__ int hist[128];
  __shared__ float sn[4], sz[4];
  if (tid < 128) hist[tid] = 0;
  __syncthreads();
  for (int i = tid; i < N_ROWS; i += 256) atomicAdd(&hist[labels[i]], 1);
  __syncthreads();

  float num = 0.f, nnz = 0.f;
  for (int i = tid; i < N_ROWS; i += 256) {
    int c = hist[labels[i]] - 1;
    num += (float)c * logf(den[i]) - pos[i];
    nnz += (float)c;
  }
#pragma unroll
  for (int m = 1; m < 64; m <<= 1) {
    num += __shfl_xor(num, m, 64);
    nnz += __shfl_xor(nnz, m, 64);
  }
  if ((tid & 63) == 0) { sn[tid >> 6] = num; sz[tid >> 6] = nnz; }
  __syncthreads();
  if (tid == 0) {
    float tn = sn[0] + sn[1] + sn[2] + sn[3];
    float tz = sz[0] + sz[1] + sz[2] + sz[3];
    out[0] = tn / (tz + EPS_DEN);
  }
}

extern "C" void kernel_launch(void* const* d_in, const int* in_sizes, int n_in,
                              void* d_out, int out_size, void* d_ws, size_t ws_size,
                              hipStream_t stream) {
  const float* x = (const float*)d_in[0];
  const int* labels = (const int*)d_in[1];

  // ws layout: fb (bf16 4096x512 = 4MB) | den f32[4096] | pos f32[4096]
  u16* fb = (u16*)d_ws;
  float* den = (float*)((char*)d_ws + (size_t)N_ROWS * DIM * 2);
  float* pos = den + N_ROWS;
  float* out = (float*)d_out;

  hipLaunchKernelGGL(k1_normalize, dim3(N_ROWS / 4), dim3(256), 0, stream,
                     x, fb, den, pos);
  hipLaunchKernelGGL(k2_fused, dim3(NBLK_I * (N_ROWS / JSPAN)), dim3(256), 0, stream,
                     fb, labels, den, pos);
  hipLaunchKernelGGL(k3_final, dim3(1), dim3(256), 0, stream,
                     den, pos, labels, out);
}